// Round 2
// baseline (446.360 us; speedup 1.0000x reference)
//
#include <hip/hip_runtime.h>
#include <stdint.h>

typedef short  s16x8 __attribute__((ext_vector_type(8)));
typedef float  f32x4 __attribute__((ext_vector_type(4)));

#define HIDDEN 768
#define SEQ    256
#define BATCH  4
#define NPAIR  32896   /* 256*257/2 */

// ---- fp32 -> bf16 round-to-nearest-even ----
__device__ inline unsigned short f2bf(float f) {
    unsigned int u = __float_as_uint(f);
    u += 0x7FFFu + ((u >> 16) & 1u);
    return (unsigned short)(u >> 16);
}

__device__ inline f32x4 tanh4(f32x4 x) {
    f32x4 o;
#pragma unroll
    for (int c = 0; c < 4; ++c) {
        const float e = __expf(2.0f * x[c]);
        o[c] = 1.0f - 2.0f * __builtin_amdgcn_rcpf(e + 1.0f);  // sat-correct at +-inf
    }
    return o;
}

// ---- Kernel 1: cast X (1024x768 fp32) -> Xb bf16 ----
__global__ void cast_x(const float* __restrict__ X, unsigned short* __restrict__ Xb) {
    int idx = blockIdx.x * 256 + threadIdx.x;
    f32x4 v = ((const f32x4*)X)[idx];
    ushort4 o;
    o.x = f2bf(v[0]); o.y = f2bf(v[1]); o.z = f2bf(v[2]); o.w = f2bf(v[3]);
    ((ushort4*)Xb)[idx] = o;
}

// ---- Kernel 2: transpose+cast W halves: Wt[n][k] bf16 ----
__global__ void transpose_w(const float* __restrict__ W, unsigned short* __restrict__ Wt) {
    __shared__ float tile[32][33];
    const float*     Wh  = W  + (size_t)blockIdx.z * HIDDEN * HIDDEN;
    unsigned short*  Wth = Wt + (size_t)blockIdx.z * HIDDEN * HIDDEN;
    int tx = threadIdx.x, ty = threadIdx.y;
    int k0 = blockIdx.x * 32, n0 = blockIdx.y * 32;
#pragma unroll
    for (int r = 0; r < 4; ++r)
        tile[ty + 8*r][tx] = Wh[(size_t)(k0 + ty + 8*r) * HIDDEN + n0 + tx];
    __syncthreads();
#pragma unroll
    for (int r = 0; r < 4; ++r)
        Wth[(size_t)(n0 + ty + 8*r) * HIDDEN + k0 + tx] = f2bf(tile[tx][ty + 8*r]);
}

// ---- Kernel 3: barrier-free direct-from-global MFMA GEMM.
//      One wave computes one 16x16 C tile; K-loop 24 x mfma_16x16x32.
//      grid (24, 64): x*64 + wave*16 = column over [W1|W2] (0..1535), y*16 = m.
//      No LDS, no barriers; Xb (1.5MB) + Wt (2.4MB) are L2-resident.
__global__ __launch_bounds__(256) void gemm_direct(const unsigned short* __restrict__ Xb,
                                                   const unsigned short* __restrict__ Wt,
                                                   const float* __restrict__ bias,
                                                   float* __restrict__ L,
                                                   float* __restrict__ R) {
    const int t = threadIdx.x;
    const int w = t >> 6, lane = t & 63, quad = lane >> 4, l16 = lane & 15;
    const int m0 = blockIdx.y * 16;
    const int c0 = blockIdx.x * 64 + w * 16;   // column tile base, 0..1520

    const unsigned short* Ap = Xb + (size_t)(m0 + l16) * HIDDEN + quad * 8;  // A[m][k]
    const unsigned short* Bp = Wt + (size_t)(c0 + l16) * HIDDEN + quad * 8;  // B^T[n][k]

    f32x4 acc = {0, 0, 0, 0};
#pragma unroll 6
    for (int kk = 0; kk < 24; ++kk) {
        s16x8 a  = *(const s16x8*)(Ap + kk * 32);
        s16x8 bf = *(const s16x8*)(Bp + kk * 32);
        acc = __builtin_amdgcn_mfma_f32_16x16x32_bf16(a, bf, acc, 0, 0, 0);
    }

    const int  c   = c0 + l16;
    const bool isL = c < HIDDEN;                // wave-uniform (c0 % 16 == 0)
    float*     dst = isL ? L : R;
    const int  n   = isL ? c : c - HIDDEN;
    const float badd = isL ? bias[n] : 0.0f;    // bias folded into L
#pragma unroll
    for (int r = 0; r < 4; ++r) {
        const int m = m0 + quad * 4 + r;        // row = quad*4 + reg, col = lane&15
        dst[(size_t)m * HIDDEN + n] = acc[r] + badd;
    }
}

// ---- Kernel 4: pair expansion, 2D-tiled. Block = 4 i-rows x 8 j-chunk, 192 thr.
//      grid (64 i-tiles, 32 j-chunks, 4 batch); blocks with j-chunk fully left
//      of the diagonal exit early. Reads: 4 L rows (regs) + 8 R rows (streamed,
//      shared across concurrent i-tile blocks -> L2 hits). Writes: contiguous
//      3KB runs per (i,j), nontemporal.
__global__ __launch_bounds__(192) void expand2(const float* __restrict__ L,
                                               const float* __restrict__ R,
                                               float* __restrict__ out) {
    const int ti = blockIdx.x, jc = blockIdx.y, b = blockIdx.z, t = threadIdx.x;
    const int i0 = ti * 4;
    const int j0 = jc * 8;
    const int jend = j0 + 8;
    if (jend <= i0) return;                     // entire chunk below diagonal
    const int jstart = (j0 > i0) ? j0 : i0;

    const f32x4* Lp = (const f32x4*)L + (size_t)(b * SEQ + i0) * 192 + t;
    const f32x4 l0 = Lp[0], l1 = Lp[192], l2 = Lp[384], l3 = Lp[576];

    const f32x4* Rp = (const f32x4*)R + (size_t)(b * SEQ) * 192 + t;

    // triangular row base: p(i,j) = T(i) + (j - i), T(i) = i*(513-i)/2
    const size_t ob = (size_t)b * NPAIR;
    const size_t p0 = ob + (size_t)((i0    ) * (513 - (i0    )) / 2 - (i0    ));
    const size_t p1 = ob + (size_t)((i0 + 1) * (513 - (i0 + 1)) / 2 - (i0 + 1));
    const size_t p2 = ob + (size_t)((i0 + 2) * (513 - (i0 + 2)) / 2 - (i0 + 2));
    const size_t p3 = ob + (size_t)((i0 + 3) * (513 - (i0 + 3)) / 2 - (i0 + 3));
    f32x4* Op = (f32x4*)out + t;

    f32x4 r = Rp[(size_t)jstart * 192];
    for (int j = jstart; j < jend; ++j) {
        f32x4 rn = r;
        if (j + 1 < jend) rn = Rp[(size_t)(j + 1) * 192];   // prefetch next R row
        // masks are wave-uniform; j >= i0+3 (common case) keeps all four
        __builtin_nontemporal_store(tanh4(l0 + r), Op + (p0 + j) * 192);
        if (j >= i0 + 1) __builtin_nontemporal_store(tanh4(l1 + r), Op + (p1 + j) * 192);
        if (j >= i0 + 2) __builtin_nontemporal_store(tanh4(l2 + r), Op + (p2 + j) * 192);
        if (j >= i0 + 3) __builtin_nontemporal_store(tanh4(l3 + r), Op + (p3 + j) * 192);
        r = rn;
    }
}

extern "C" void kernel_launch(void* const* d_in, const int* in_sizes, int n_in,
                              void* d_out, int out_size, void* d_ws, size_t ws_size,
                              hipStream_t stream) {
    const float* X = (const float*)d_in[0];   // (4,256,768)
    const float* W = (const float*)d_in[1];   // (1536,768)
    const float* b = (const float*)d_in[2];   // (768,)
    float* out = (float*)d_out;               // (4,32896,768) fp32

    char* ws = (char*)d_ws;
    unsigned short* Xb = (unsigned short*)(ws);              // 1,572,864 B
    unsigned short* Wt = (unsigned short*)(ws + 1572864);    // 2,359,296 B
    float*          L  = (float*)(ws + 3932160);             // 3,145,728 B (bias folded)
    float*          R  = (float*)(ws + 7077888);             // 3,145,728 B

    hipLaunchKernelGGL(cast_x,      dim3(768),        dim3(256),   0, stream, X, Xb);
    hipLaunchKernelGGL(transpose_w, dim3(24, 24, 2),  dim3(32, 8), 0, stream, W, Wt);
    hipLaunchKernelGGL(gemm_direct, dim3(24, 64),     dim3(256),   0, stream, Xb, Wt, b, L, R);
    hipLaunchKernelGGL(expand2,     dim3(64, 32, 4),  dim3(192),   0, stream, L, R, out);
}